// Round 1
// 1294.802 us; speedup vs baseline: 1.1048x; 1.1048x over previous
//
#include <hip/hip_runtime.h>
#include <hip/hip_bf16.h>

#define NN   100000
#define EE   3200000
#define INF  512
#define HIDF 256
#define OUTF 64
#define KSTEPS 10

typedef __attribute__((ext_vector_type(8))) short short8;
typedef __attribute__((ext_vector_type(4))) float floatx4;
typedef unsigned short ushort_t;

static __device__ inline short bf2s(__hip_bfloat16 h) {
    return __builtin_bit_cast(short, h);
}

// manual round-to-nearest-even f32 -> bf16 (finite inputs)
static __device__ inline unsigned short f2bf(float f) {
    unsigned u = __float_as_uint(f);
    unsigned r = (u + 0x7FFFu + ((u >> 16) & 1u)) >> 16;
    return (unsigned short)r;
}

static __device__ inline float b2f(unsigned short u) {
    return __uint_as_float(((unsigned)u) << 16);
}

// ---------------- setup kernels ----------------

__global__ void zero_kernel(int* p, int n) {
    int i = blockIdx.x * 256 + threadIdx.x;
    if (i < n) p[i] = 0;
}

__global__ void count_kernel(const int* __restrict__ ei, int* __restrict__ counts) {
    int e = blockIdx.x * 256 + threadIdx.x;
    if (e < EE) atomicAdd(&counts[ei[EE + e]], 1);
}

__global__ void dinv_kernel(const int* __restrict__ counts, float* __restrict__ dinv) {
    int i = blockIdx.x * 256 + threadIdx.x;
    if (i < NN) dinv[i] = rsqrtf((float)(counts[i] + 1));  // +1 self loop
}

// chunk=256 exclusive scan, per-block
__global__ void scan1(const int* __restrict__ counts, int* __restrict__ offs,
                      int* __restrict__ partial) {
    __shared__ int s[256];
    int tid = threadIdx.x;
    int i = blockIdx.x * 256 + tid;
    int v = (i < NN) ? counts[i] : 0;
    s[tid] = v;
    __syncthreads();
    for (int d = 1; d < 256; d <<= 1) {
        int t = (tid >= d) ? s[tid - d] : 0;
        __syncthreads();
        s[tid] += t;
        __syncthreads();
    }
    if (i < NN) offs[i] = s[tid] - v;     // exclusive within block
    if (tid == 255) partial[blockIdx.x] = s[255];
}

__global__ void scan2(int* partial, int nblocks) {
    __shared__ int s[512];
    int tid = threadIdx.x;
    int v = (tid < nblocks) ? partial[tid] : 0;
    s[tid] = v;
    __syncthreads();
    for (int d = 1; d < 512; d <<= 1) {
        int t = (tid >= d) ? s[tid - d] : 0;
        __syncthreads();
        s[tid] += t;
        __syncthreads();
    }
    if (tid < nblocks) partial[tid] = s[tid] - v;  // exclusive block bases
}

__global__ void scan3(int* __restrict__ offs, const int* __restrict__ partial) {
    int i = blockIdx.x * 256 + threadIdx.x;
    if (i < NN) offs[i] += partial[i >> 8];
    else if (i == NN) offs[NN] = EE;
}

// countdown-fill: reuses counts[] as cursor (counts destroyed here)
__global__ void fill_kernel(const int* __restrict__ ei, const int* __restrict__ offs,
                            int* __restrict__ counts, int* __restrict__ srcIdx) {
    int e = blockIdx.x * 256 + threadIdx.x;
    if (e >= EE) return;
    int r = ei[e];        // source (gathered from)
    int c = ei[EE + e];   // target (aggregated into)
    int old = atomicSub(&counts[c], 1);
    srcIdx[offs[c] + old - 1] = r;
}

// pack W1 into per-lane MFMA B-fragment order:
// dst[((kk*16+t)*64 + q*16 + l)*8 + jj] = bf16(W1[kk*32+q*8+jj][t*16+l])
__global__ void pack_w1(const float* __restrict__ W1, short* __restrict__ W1p) {
    int id = blockIdx.x * 256 + threadIdx.x;
    if (id >= INF * HIDF) return;
    int jj = id & 7, l = (id >> 3) & 15, q = (id >> 7) & 3, t = (id >> 9) & 15, kk = id >> 13;
    int k = kk * 32 + q * 8 + jj, n = t * 16 + l;
    W1p[id] = (short)f2bf(W1[k * HIDF + n]);
}

__global__ void pack_w2(const float* __restrict__ W2, short* __restrict__ W2p) {
    int id = blockIdx.x * 256 + threadIdx.x;
    if (id >= HIDF * OUTF) return;
    int jj = id & 7, l = (id >> 3) & 15, q = (id >> 7) & 3, t = (id >> 9) & 3, kk = id >> 11;
    int k = kk * 32 + q * 8 + jj, n = t * 16 + l;
    W2p[id] = (short)f2bf(W2[k * OUTF + n]);
}

// ---------------- fused MLP: h = relu(x@W1+b1)@W2+b2 ----------------
// writes z0 = bf16(dinv*h) and out = temp[0]*h

__global__ __launch_bounds__(256) void mlp_kernel(
    const float* __restrict__ x, const short* __restrict__ W1p,
    const short* __restrict__ W2p, const float* __restrict__ b1,
    const float* __restrict__ b2, const float* __restrict__ temp,
    const float* __restrict__ dinv,
    ushort_t* __restrict__ z0, float* __restrict__ out) {

    __shared__ __align__(16) short hlds[64][HIDF + 8];

    int tid = threadIdx.x;
    int wave = tid >> 6, lane = tid & 63;
    int l16 = lane & 15, quad = lane >> 4;
    int brow = blockIdx.x * 64;

    const floatx4 zf = {0.f, 0.f, 0.f, 0.f};
    floatx4 acc[4][4];
#pragma unroll
    for (int mi = 0; mi < 4; mi++)
#pragma unroll
        for (int j = 0; j < 4; j++) acc[mi][j] = zf;

    // row base pointers (clamped for tail block; stores masked later)
    const float* rp[4];
#pragma unroll
    for (int mi = 0; mi < 4; mi++) {
        int row = brow + mi * 16 + l16;
        if (row > NN - 1) row = NN - 1;
        rp[mi] = x + (size_t)row * INF + quad * 8;
    }

    // GEMM1: rows [brow,brow+64) x cols [wave*64, wave*64+64), K=512
    for (int kk = 0; kk < 16; kk++) {
        short8 a[4];
#pragma unroll
        for (int mi = 0; mi < 4; mi++) {
            const float4* ap = reinterpret_cast<const float4*>(rp[mi] + kk * 32);
            float4 f0 = ap[0];
            float4 f1 = ap[1];
            __hip_bfloat162 q0 = __float22bfloat162_rn(make_float2(f0.x, f0.y));
            __hip_bfloat162 q1 = __float22bfloat162_rn(make_float2(f0.z, f0.w));
            __hip_bfloat162 q2 = __float22bfloat162_rn(make_float2(f1.x, f1.y));
            __hip_bfloat162 q3 = __float22bfloat162_rn(make_float2(f1.z, f1.w));
            short8 av;
            av[0] = bf2s(q0.x); av[1] = bf2s(q0.y);
            av[2] = bf2s(q1.x); av[3] = bf2s(q1.y);
            av[4] = bf2s(q2.x); av[5] = bf2s(q2.y);
            av[6] = bf2s(q3.x); av[7] = bf2s(q3.y);
            a[mi] = av;
        }
        short8 b[4];
#pragma unroll
        for (int j = 0; j < 4; j++) {
            int t = wave * 4 + j;
            b[j] = *reinterpret_cast<const short8*>(
                W1p + (((size_t)(kk * 16 + t) * 64 + quad * 16 + l16) << 3));
        }
#pragma unroll
        for (int mi = 0; mi < 4; mi++)
#pragma unroll
            for (int j = 0; j < 4; j++)
                acc[mi][j] = __builtin_amdgcn_mfma_f32_16x16x32_bf16(a[mi], b[j], acc[mi][j], 0, 0, 0);
    }

    // bias + relu -> LDS (bf16), C-layout: D[row=quad*4+r][col=l16]
#pragma unroll
    for (int j = 0; j < 4; j++) {
        float bj = b1[wave * 64 + j * 16 + l16];
#pragma unroll
        for (int mi = 0; mi < 4; mi++)
#pragma unroll
            for (int r = 0; r < 4; r++) {
                float v = acc[mi][j][r] + bj;
                v = fmaxf(v, 0.f);
                hlds[mi * 16 + quad * 4 + r][wave * 64 + j * 16 + l16] = (short)f2bf(v);
            }
    }
    __syncthreads();

    // GEMM2: wave handles rows [wave*16, wave*16+16) x 64 out cols, K=256
    floatx4 acc2[4];
#pragma unroll
    for (int j = 0; j < 4; j++) acc2[j] = zf;

#pragma unroll
    for (int kk = 0; kk < 8; kk++) {
        short8 a2 = *reinterpret_cast<const short8*>(&hlds[wave * 16 + l16][kk * 32 + quad * 8]);
#pragma unroll
        for (int j = 0; j < 4; j++) {
            short8 bb = *reinterpret_cast<const short8*>(
                W2p + (((size_t)(kk * 4 + j) * 64 + quad * 16 + l16) << 3));
            acc2[j] = __builtin_amdgcn_mfma_f32_16x16x32_bf16(a2, bb, acc2[j], 0, 0, 0);
        }
    }

    float t0 = temp[0];
#pragma unroll
    for (int j = 0; j < 4; j++) {
        float bb = b2[j * 16 + l16];
#pragma unroll
        for (int r = 0; r < 4; r++) {
            int row = brow + wave * 16 + quad * 4 + r;
            if (row < NN) {
                float v = acc2[j][r] + bb;
                size_t o = (size_t)row * 64 + j * 16 + l16;
                out[o] = t0 * v;
                z0[o] = f2bf(dinv[row] * v);
            }
        }
    }
}

// ---------------- propagation: one wave per target node ----------------
// Wide-gather layout: lane = (g, q), g = lane>>3 picks one of 8 edges per
// load instruction, q = lane&7 owns features q*8..q*8+7 (16B of bf16).
// Each lane loads dwordx4 (16B) per edge -> 8 edges per wave per VMEM instr,
// 2-deep unroll -> 2KB outstanding per wave (4x the old 2B/lane scheme).
// acc = z[self] + sum z[src]; cn = dinv*acc; hid += temp[k]*cn;
// z' = bf16(dinv*cn).

#define BLO(u) __uint_as_float((u) << 16)
#define BHI(u) __uint_as_float((u) & 0xFFFF0000u)
#define ACC8(v)                      \
    do {                             \
        a0 += BLO((v).x);            \
        a1 += BHI((v).x);            \
        a2 += BLO((v).y);            \
        a3 += BHI((v).y);            \
        a4 += BLO((v).z);            \
        a5 += BHI((v).z);            \
        a6 += BLO((v).w);            \
        a7 += BHI((v).w);            \
    } while (0)

__global__ __launch_bounds__(256, 8) void prop_kernel(
    const int* __restrict__ srcIdx, const int* __restrict__ offs,
    const float* __restrict__ dinv, const ushort_t* __restrict__ z,
    ushort_t* __restrict__ zn, float* __restrict__ hid,
    const float* __restrict__ temp, int k, int write_z) {

    int node = blockIdx.x * 4 + (threadIdx.x >> 6);   // NN = 4*25000 exactly
    int lane = threadIdx.x & 63;
    int g = lane >> 3;   // edge slot within the 8-edge group
    int q = lane & 7;    // feature octet

    int beg = __builtin_amdgcn_readfirstlane(offs[node]);
    int end = __builtin_amdgcn_readfirstlane(offs[node + 1]);

    float a0 = 0.f, a1 = 0.f, a2 = 0.f, a3 = 0.f;
    float a4 = 0.f, a5 = 0.f, a6 = 0.f, a7 = 0.f;

    // self-loop term: whole wave loads (line broadcast), only group 0 adds
    {
        uint4 v = reinterpret_cast<const uint4*>(z + ((size_t)node << 6))[q];
        if (g == 0) ACC8(v);
    }

    int e = beg;
    // main loop: 16 edges per iteration, 2 independent 16B gathers in flight
    for (; e + 16 <= end; e += 16) {
        int s0 = srcIdx[e + g];
        int s1 = srcIdx[e + 8 + g];
        uint4 v0 = reinterpret_cast<const uint4*>(z + ((size_t)s0 << 6))[q];
        uint4 v1 = reinterpret_cast<const uint4*>(z + ((size_t)s1 << 6))[q];
        ACC8(v0);
        ACC8(v1);
    }
    // tail: 8 edges at a time, clamp+predicate
    for (; e < end; e += 8) {
        int ee = e + g;
        int cl = (ee < end) ? ee : (end - 1);
        int s = srcIdx[cl];
        uint4 v = reinterpret_cast<const uint4*>(z + ((size_t)s << 6))[q];
        if (ee < end) ACC8(v);
    }

    // butterfly reduce across the 8 edge-groups (lane bits 3,4,5)
#pragma unroll
    for (int m = 8; m < 64; m <<= 1) {
        a0 += __shfl_xor(a0, m);
        a1 += __shfl_xor(a1, m);
        a2 += __shfl_xor(a2, m);
        a3 += __shfl_xor(a3, m);
        a4 += __shfl_xor(a4, m);
        a5 += __shfl_xor(a5, m);
        a6 += __shfl_xor(a6, m);
        a7 += __shfl_xor(a7, m);
    }

    float dv = dinv[node];
    float tk = temp[k];
    float c0 = dv * a0, c1 = dv * a1, c2 = dv * a2, c3 = dv * a3;
    float c4 = dv * a4, c5 = dv * a5, c6 = dv * a6, c7 = dv * a7;

    if (g == 0) {
        float* hp = hid + ((size_t)node << 6) + q * 8;
        float4 h0 = *reinterpret_cast<float4*>(hp);
        float4 h1 = *reinterpret_cast<float4*>(hp + 4);
        h0.x += tk * c0; h0.y += tk * c1; h0.z += tk * c2; h0.w += tk * c3;
        h1.x += tk * c4; h1.y += tk * c5; h1.z += tk * c6; h1.w += tk * c7;
        *reinterpret_cast<float4*>(hp) = h0;
        *reinterpret_cast<float4*>(hp + 4) = h1;
        if (write_z) {
            uint4 u;
            u.x = (unsigned)f2bf(dv * c0) | ((unsigned)f2bf(dv * c1) << 16);
            u.y = (unsigned)f2bf(dv * c2) | ((unsigned)f2bf(dv * c3) << 16);
            u.z = (unsigned)f2bf(dv * c4) | ((unsigned)f2bf(dv * c5) << 16);
            u.w = (unsigned)f2bf(dv * c6) | ((unsigned)f2bf(dv * c7) << 16);
            reinterpret_cast<uint4*>(zn + ((size_t)node << 6))[q] = u;
        }
    }
}

// ---------------- launch ----------------

extern "C" void kernel_launch(void* const* d_in, const int* in_sizes, int n_in,
                              void* d_out, int out_size, void* d_ws, size_t ws_size,
                              hipStream_t stream) {
    const float* x    = (const float*)d_in[0];
    const int*   ei   = (const int*)d_in[1];   // [2,E] int32 (harness converts int64)
    const float* W1   = (const float*)d_in[2];
    const float* b1   = (const float*)d_in[3];
    const float* W2   = (const float*)d_in[4];
    const float* b2   = (const float*)d_in[5];
    const float* temp = (const float*)d_in[6];
    float* out = (float*)d_out;

    char* p = (char*)d_ws;
    auto carve = [&](size_t bytes) -> char* {
        char* r = p;
        p += (bytes + 255) & ~(size_t)255;
        return r;
    };
    ushort_t* zA   = (ushort_t*)carve(sizeof(ushort_t) * (size_t)NN * 64);
    ushort_t* zB   = (ushort_t*)carve(sizeof(ushort_t) * (size_t)NN * 64);
    int* srcIdx    = (int*)carve(sizeof(int) * (size_t)EE);
    int* counts    = (int*)carve(sizeof(int) * NN);
    int* offs      = (int*)carve(sizeof(int) * (NN + 1));
    int* partial   = (int*)carve(sizeof(int) * 512);
    float* dinv    = (float*)carve(sizeof(float) * NN);
    short* W1p     = (short*)carve(sizeof(short) * INF * HIDF);
    short* W2p     = (short*)carve(sizeof(short) * HIDF * OUTF);

    const int NB = (NN + 255) / 256;      // 391

    zero_kernel<<<NB, 256, 0, stream>>>(counts, NN);
    pack_w1<<<(INF * HIDF + 255) / 256, 256, 0, stream>>>(W1, W1p);
    pack_w2<<<(HIDF * OUTF + 255) / 256, 256, 0, stream>>>(W2, W2p);

    count_kernel<<<EE / 256, 256, 0, stream>>>(ei, counts);
    dinv_kernel<<<NB, 256, 0, stream>>>(counts, dinv);
    scan1<<<NB, 256, 0, stream>>>(counts, offs, partial);
    scan2<<<1, 512, 0, stream>>>(partial, NB);
    scan3<<<(NN + 256) / 256, 256, 0, stream>>>(offs, partial);
    fill_kernel<<<EE / 256, 256, 0, stream>>>(ei, offs, counts, srcIdx);

    mlp_kernel<<<(NN + 63) / 64, 256, 0, stream>>>(x, W1p, W2p, b1, b2, temp, dinv, zA, out);

    ushort_t* a = zA;
    ushort_t* b = zB;
    for (int k = 1; k <= KSTEPS; k++) {
        prop_kernel<<<NN / 4, 256, 0, stream>>>(srcIdx, offs, dinv, a, b, out, temp, k,
                                                (k < KSTEPS) ? 1 : 0);
        ushort_t* t = a; a = b; b = t;
    }
}